// Round 8
// baseline (3511.116 us; speedup 1.0000x reference)
//
#include <hip/hip_runtime.h>

// SCRN: 2 layers of { xp = x@Wx^T+bx ; c_t = .05c+.95xp ; h_t = tanh(c@Uc^T + h@Vh^T) } + fc.
// EMA decay 0.05 -> 16-tap filter (parallel). d = c@Uc^T parallel GEMM (time-major).
// Recurrence (round-8): ZERO-EXCHANGE. 4 blocks, one per 16 batch rows, full 512 hid cols per
// block. 512 thr = 8 waves; per wave 64 out-cols: Vh 12 K-chunks in REGISTERS (192 VGPR) +
// 4 K-chunks in LDS (fragment-major, conflict-free); h[16][512] in LDS, 2 barriers/step.
// Needs 147712 B dynamic LDS -> runtime check MaxSharedMemoryPerBlock; fallback = round-7
// community-2 tagged-LLC-exchange scan (rounds 4-7 lesson: LLC exchange floors at ~2.5us/step).

typedef _Float16 f16;
typedef _Float16 f16x8 __attribute__((ext_vector_type(8)));
typedef _Float16 f16x2 __attribute__((ext_vector_type(2)));
typedef float f32x4 __attribute__((ext_vector_type(4)));
typedef unsigned short u16;
typedef unsigned int u32;
typedef unsigned short u16x8 __attribute__((ext_vector_type(8)));
typedef unsigned long long u64;

#define DEV __device__ __forceinline__

constexpr int Tt = 512, HIDq = 512;
constexpr int SCAN4_LDS = 147712;   // hL 16*520*2 + BL 8*4*4*64*8*2

DEV float bf2f(u16 u) { unsigned v = ((unsigned)u) << 16; float f; __builtin_memcpy(&f, &v, 4); return f; }
DEV u16 f2bf(float f) { unsigned u; __builtin_memcpy(&u, &f, 4); u = (u + 0x7fffu + ((u >> 16) & 1u)) >> 16; return (u16)u; }
DEV float fast_tanh(float x) {
  x = fminf(30.f, fmaxf(-30.f, x));
  float e = exp2f(x * 2.885390081777927f);   // e^(2x)
  return (e - 1.f) / (e + 1.f);
}
DEV u64 al64(const u64* p) { return __hip_atomic_load(p, __ATOMIC_RELAXED, __HIP_MEMORY_SCOPE_AGENT); }
DEV void as32(u32* p, u32 v) { __hip_atomic_store(p, v, __ATOMIC_RELAXED, __HIP_MEMORY_SCOPE_AGENT); }

// ---- dtype probe: Wx0 entries bounded by 1/16; bf16 decode of f32 mantissa halves -> huge ----
__global__ void k_probe(const u16* __restrict__ w, int* __restrict__ dmode) {
  __shared__ int s;
  if (threadIdx.x == 0) s = 0;
  __syncthreads();
  int found = 0;
  for (int i = threadIdx.x; i < 8192; i += 256) {
    float v = bf2f(w[i]);
    if (fabsf(v) > 0.5f) found = 1;
  }
  if (found) atomicOr(&s, 1);
  __syncthreads();
  if (threadIdx.x == 0) *dmode = s;   // 0 = bf16 buffers, 1 = f32 buffers
}

// ---- convert n8*8 elements (bf16 or f32 per mode) -> fp16 ----
__global__ void k_cvt(const void* __restrict__ src, f16* __restrict__ dst, int n8,
                      const int* __restrict__ dmode) {
  int i = blockIdx.x * 256 + threadIdx.x;
  if (i >= n8) return;
  f16x8 o;
  if (*dmode) {
    const float4* s = (const float4*)src;
    float4 a = s[2*i], b = s[2*i+1];
    o[0]=(f16)a.x; o[1]=(f16)a.y; o[2]=(f16)a.z; o[3]=(f16)a.w;
    o[4]=(f16)b.x; o[5]=(f16)b.y; o[6]=(f16)b.z; o[7]=(f16)b.w;
  } else {
    u16x8 v = ((const u16x8*)src)[i];
#pragma unroll
    for (int j = 0; j < 8; ++j) o[j] = (f16)bf2f(v[j]);
  }
  ((f16x8*)dst)[i] = o;
}

__global__ void k_zero(u16* __restrict__ out) {  // diagnostic fallback (ws too small)
  out[blockIdx.x * 256 + threadIdx.x] = 0;
}

// ---- EMA c_t = 0.05 c_{t-1} + 0.95 xp_t ; 16-step warmup per 64-chunk ----
__global__ __launch_bounds__(128) void k_ema(const f16* __restrict__ xp, f16* __restrict__ c) {
  int b = blockIdx.x >> 3, chunk = blockIdx.x & 7;
  int t0 = chunk * 64;
  int ch = threadIdx.x;
  const f16x2* src = (const f16x2*)(xp + (size_t)b * Tt * 256) + ch;
  f16x2* dst = (f16x2*)(c + (size_t)b * Tt * 256) + ch;
  float c0 = 0.f, c1 = 0.f;
  int ts = (t0 >= 16) ? t0 - 16 : 0;
  for (int tt = ts; tt < t0 + 64; ++tt) {
    f16x2 v = src[(size_t)tt * 128];
    c0 = 0.05f * c0 + 0.95f * (float)v.x;
    c1 = 0.05f * c1 + 0.95f * (float)v.y;
    if (tt >= t0) { f16x2 o; o.x = (f16)c0; o.y = (f16)c1; dst[(size_t)tt * 128] = o; }
  }
}

// ---- GEMM: C = A[M,K] @ B[N,K]^T (+bias). TD: store C time-major (row b*512+t -> t*64+b) ----
template<bool HAS_BIAS, bool TD>
__global__ __launch_bounds__(256) void k_gemm(const f16* __restrict__ A, const f16* __restrict__ Bm,
                                              const f16* __restrict__ bias, f16* __restrict__ C,
                                              int M, int N, int K) {
  __shared__ f16 As[128][40];
  __shared__ f16 Bs[128][40];
  const int tid = threadIdx.x, lane = tid & 63, wv = tid >> 6;
  const int l15 = lane & 15, q = lane >> 4;
  const int wm = wv >> 1, wn = wv & 1;
  const int m0 = blockIdx.y * 128, n0 = blockIdx.x * 128;
  const int srow = tid >> 1, sseg = tid & 1;
  f32x4 acc[4][4] = {};
  const f16* ga = A  + (size_t)(m0 + srow) * K + sseg * 16;
  const f16* gb = Bm + (size_t)(n0 + srow) * K + sseg * 16;
  for (int k0 = 0; k0 < K; k0 += 32) {
    f16x8 a0 = *(const f16x8*)(ga + k0);
    f16x8 a1 = *(const f16x8*)(ga + k0 + 8);
    f16x8 b0 = *(const f16x8*)(gb + k0);
    f16x8 b1 = *(const f16x8*)(gb + k0 + 8);
    __syncthreads();
    *(f16x8*)&As[srow][sseg*16]     = a0;
    *(f16x8*)&As[srow][sseg*16 + 8] = a1;
    *(f16x8*)&Bs[srow][sseg*16]     = b0;
    *(f16x8*)&Bs[srow][sseg*16 + 8] = b1;
    __syncthreads();
    f16x8 af[4], bf[4];
#pragma unroll
    for (int i = 0; i < 4; ++i) af[i] = *(const f16x8*)&As[wm*64 + i*16 + l15][q*8];
#pragma unroll
    for (int i = 0; i < 4; ++i) bf[i] = *(const f16x8*)&Bs[wn*64 + i*16 + l15][q*8];
#pragma unroll
    for (int i = 0; i < 4; ++i)
#pragma unroll
      for (int j = 0; j < 4; ++j)
        acc[i][j] = __builtin_amdgcn_mfma_f32_16x16x32_f16(af[i], bf[j], acc[i][j], 0, 0, 0);
  }
#pragma unroll
  for (int j = 0; j < 4; ++j) {
    int col = n0 + wn*64 + j*16 + l15;
    float bv = HAS_BIAS ? (float)bias[col] : 0.f;
#pragma unroll
    for (int i = 0; i < 4; ++i)
#pragma unroll
      for (int r = 0; r < 4; ++r) {
        int row = m0 + wm*64 + i*16 + q*4 + r;
        size_t orow = TD ? (size_t)((row & 511) * 64 + (row >> 9)) : (size_t)row;
        C[orow * N + col] = (f16)(acc[i][j][r] + bv);
      }
  }
}

// ---- BIG-LDS scan: zero-exchange. 4 blocks (16 batch rows each), 512 thr = 8 waves. ----
// Wave w: out cols 64w..+63 (4 tiles). Vh: chunks 0..11 in regs Bf[12][4]; chunks 12..15 in LDS
// fragment-major (lane-consecutive 16B => conflict-free). hL[16][520] single buffer.
__global__ __launch_bounds__(512) void k_scan4(const f16* __restrict__ Vh,
                                               const f16* __restrict__ d2,
                                               f16* __restrict__ hs_out,
                                               f16* __restrict__ hlast) {
  extern __shared__ f16 smem[];
  f16* hL = smem;                  // 16 x 520
  f16* BL = smem + 16 * 520;       // ((w*4+c)*4+j)*64+lane, 8 f16 each
  const int g = blockIdx.x;
  const int tid = threadIdx.x, w = tid >> 6, lane = tid & 63;
  const int l15 = lane & 15, q = lane >> 4;

  // stage Vh: regs (chunks 0..11) + LDS (chunks 12..15)
  f16x8 Bf[12][4];
#pragma unroll
  for (int kk = 0; kk < 12; ++kk)
#pragma unroll
    for (int j = 0; j < 4; ++j)
      Bf[kk][j] = *(const f16x8*)&Vh[(size_t)(64*w + 16*j + l15) * HIDq + kk*32 + q*8];
#pragma unroll
  for (int c = 0; c < 4; ++c)
#pragma unroll
    for (int j = 0; j < 4; ++j) {
      f16x8 v = *(const f16x8*)&Vh[(size_t)(64*w + 16*j + l15) * HIDq + (12+c)*32 + q*8];
      *(f16x8*)&BL[(size_t)(((w*4 + c)*4 + j)*64 + lane) * 8] = v;
    }
  // h_{-1} = 0
  for (int i = tid; i < 1024; i += 512) {
    int r = i >> 6, cc = (i & 63) * 8;
    f16x8 z = {};
    *(f16x8*)&hL[r*520 + cc] = z;
  }
  // d_0 prefetch
  const f16* dbase = d2 + (size_t)(16*g + q*4) * HIDq + 64*w + l15;
  float dv[4][4];
#pragma unroll
  for (int j = 0; j < 4; ++j)
#pragma unroll
    for (int r = 0; r < 4; ++r)
      dv[j][r] = (float)dbase[(size_t)r * HIDq + j*16];
  __syncthreads();

  for (int t = 0; t < Tt; ++t) {
    // MFMA: 4 col-tiles x 16 K-chunks; A from hL, B from regs/LDS
    f32x4 acc[4] = {};
#pragma unroll
    for (int kk = 0; kk < 16; ++kk) {
      f16x8 a = *(const f16x8*)&hL[l15*520 + kk*32 + q*8];
      if (kk < 12) {
#pragma unroll
        for (int j = 0; j < 4; ++j)
          acc[j] = __builtin_amdgcn_mfma_f32_16x16x32_f16(a, Bf[kk][j], acc[j], 0, 0, 0);
      } else {
        const int c = kk - 12;
#pragma unroll
        for (int j = 0; j < 4; ++j) {
          f16x8 bl = *(const f16x8*)&BL[(size_t)(((w*4 + c)*4 + j)*64 + lane) * 8];
          acc[j] = __builtin_amdgcn_mfma_f32_16x16x32_f16(a, bl, acc[j], 0, 0, 0);
        }
      }
    }
    __syncthreads();   // all A-reads of h_{t-1} done
    // epilogue: tanh -> write h_t into hL (row=q*4+r, col=64w+16j+l15)
#pragma unroll
    for (int j = 0; j < 4; ++j)
#pragma unroll
      for (int r = 0; r < 4; ++r) {
        float z = acc[j][r] + dv[j][r];
        hL[(q*4 + r)*520 + 64*w + 16*j + l15] = (f16)fast_tanh(z);
      }
    __syncthreads();   // h_t complete
    // hs_out copy (coalesced b128 from LDS), hlast at t=511
    if (hs_out) {
#pragma unroll
      for (int i = tid; i < 1024; i += 512) {
        int r = i >> 6, cc = (i & 63) * 8;
        *(f16x8*)&hs_out[((size_t)(16*g + r) * Tt + t) * HIDq + cc] =
            *(const f16x8*)&hL[r*520 + cc];
      }
    }
    if (hlast && t == Tt - 1) {
#pragma unroll
      for (int i = tid; i < 1024; i += 512) {
        int r = i >> 6, cc = (i & 63) * 8;
        *(f16x8*)&hlast[(size_t)(16*g + r) * HIDq + cc] = *(const f16x8*)&hL[r*520 + cc];
      }
    }
    // d prefetch t+1
    if (t < Tt - 1) {
#pragma unroll
      for (int j = 0; j < 4; ++j)
#pragma unroll
        for (int r = 0; r < 4; ++r)
          dv[j][r] = (float)dbase[(size_t)(t+1) * 64 * HIDq + (size_t)r * HIDq + j*16];
    }
  }
}

// ---- FALLBACK scan (round-7, verbatim): community-2 tagged LLC exchange ----
__global__ __launch_bounds__(512, 2) void k_scan(const f16* __restrict__ Vh,
                                                 const f16* __restrict__ d2,
                                                 u32* __restrict__ htag,
                                                 f16* __restrict__ hs_out) {
  __shared__ f16 hL[2][16][520];
  const int bid = blockIdx.x, hf = bid & 1, g = bid >> 1;
  const int tid = threadIdx.x, w = tid >> 6, lane = tid & 63;
  const int l15 = lane & 15, q = lane >> 4;
  const int colbase = 256*hf + 32*w;
  f16x8 Bf[2][16];
#pragma unroll
  for (int j = 0; j < 2; ++j)
#pragma unroll
    for (int kk = 0; kk < 16; ++kk)
      Bf[j][kk] = *(const f16x8*)&Vh[(size_t)(colbase + 16*j + l15) * HIDq + kk*32 + q*8];
  for (int i = tid; i < 1024; i += 512) {
    int r = i >> 6, c = (i & 63) * 8;
    f16x8 z = {};
    *(f16x8*)&hL[0][r][c] = z;
  }
  float dv[2][4];
#pragma unroll
  for (int j = 0; j < 2; ++j)
#pragma unroll
    for (int r = 0; r < 4; ++r)
      dv[j][r] = (float)d2[((size_t)0*64 + 16*g + q*4 + r) * HIDq + colbase + 16*j + l15];
  __syncthreads();
  const int irow = tid >> 5, ic8 = (tid & 31) * 8;
  const int pcol = 256*(hf ^ 1) + ic8;
  for (int t = 0; t < Tt; ++t) {
    const int rb = t & 1, wb = rb ^ 1, slot = t & 1;
    if (hs_out && t > 0) {
#pragma unroll
      for (int c = tid; c < 1024; c += 512) {
        int r = c >> 6, cc = (c & 63) * 8;
        *(f16x8*)&hs_out[((size_t)(16*g + r) * Tt + (t-1)) * HIDq + cc] =
            *(const f16x8*)&hL[rb][r][cc];
      }
    }
    f32x4 a00 = {}, a01 = {}, a10 = {}, a11 = {};
#pragma unroll
    for (int kk = 0; kk < 16; ++kk) {
      f16x8 a = *(const f16x8*)&hL[rb][l15][kk*32 + q*8];
      if (kk & 1) {
        a01 = __builtin_amdgcn_mfma_f32_16x16x32_f16(a, Bf[0][kk], a01, 0, 0, 0);
        a11 = __builtin_amdgcn_mfma_f32_16x16x32_f16(a, Bf[1][kk], a11, 0, 0, 0);
      } else {
        a00 = __builtin_amdgcn_mfma_f32_16x16x32_f16(a, Bf[0][kk], a00, 0, 0, 0);
        a10 = __builtin_amdgcn_mfma_f32_16x16x32_f16(a, Bf[1][kk], a10, 0, 0, 0);
      }
    }
    const u32 tagw = (u32)(t + 1) << 16;
    u16 hbits[2][4];
#pragma unroll
    for (int j = 0; j < 2; ++j) {
      f32x4 s = j ? (a10 + a11) : (a00 + a01);
#pragma unroll
      for (int r = 0; r < 4; ++r) {
        float z = s[r] + dv[j][r];
        union { f16 h; u16 u; } cv; cv.h = (f16)fast_tanh(z);
        hbits[j][r] = cv.u;
        as32(&htag[(size_t)(slot*64 + 16*g + q*4 + r) * HIDq + colbase + 16*j + l15],
             tagw | (u32)cv.u);
      }
    }
#pragma unroll
    for (int j = 0; j < 2; ++j)
#pragma unroll
      for (int r = 0; r < 4; ++r) {
        union { u16 u; f16 h; } cv; cv.u = hbits[j][r];
        hL[wb][q*4 + r][colbase + 16*j + l15] = cv.h;
      }
    if (t < Tt - 1) {
#pragma unroll
      for (int j = 0; j < 2; ++j)
#pragma unroll
        for (int r = 0; r < 4; ++r)
          dv[j][r] = (float)d2[((size_t)(t+1)*64 + 16*g + q*4 + r) * HIDq + colbase + 16*j + l15];
    }
    {
      const u64* pp = (const u64*)&htag[(size_t)(slot*64 + 16*g + irow) * HIDq] + pcol/2;
      u64 v[4];
#pragma unroll
      for (int jj = 0; jj < 4; ++jj) v[jj] = al64(pp + jj);
      for (;;) {
        u32 bad = 0;
#pragma unroll
        for (int jj = 0; jj < 4; ++jj)
          bad |= ((u32)v[jj] ^ tagw) | ((u32)(v[jj] >> 32) ^ tagw);
        if ((bad & 0xFFFF0000u) == 0) break;
#pragma unroll
        for (int jj = 0; jj < 4; ++jj) v[jj] = al64(pp + jj);
      }
      union { u32 wd[4]; f16x8 vv; } fr;
#pragma unroll
      for (int jj = 0; jj < 4; ++jj)
        fr.wd[jj] = __builtin_amdgcn_perm((u32)(v[jj] >> 32), (u32)v[jj], 0x05040100u);
      *(f16x8*)&hL[wb][irow][pcol] = fr.vv;
    }
    __syncthreads();
  }
  if (hs_out) {
#pragma unroll
    for (int c = tid; c < 1024; c += 512) {
      int r = c >> 6, cc = (c & 63) * 8;
      *(f16x8*)&hs_out[((size_t)(16*g + r) * Tt + (Tt-1)) * HIDq + cc] =
          *(const f16x8*)&hL[0][r][cc];
    }
  }
}

// ---- final (big path): out = h_last[64,512] @ fc_w^T + fc_b; h plain f16 ----
__global__ __launch_bounds__(64) void k_final16(const f16* __restrict__ h, const f16* __restrict__ fw,
                                                const f16* __restrict__ fb, void* __restrict__ outv,
                                                const int* __restrict__ dmode) {
  __shared__ f16 hA[16][520];
  __shared__ f16 Bw[16][520];
  const int mb = blockIdx.x & 3, nb = blockIdx.x >> 2;
  const int lane = threadIdx.x, l15 = lane & 15, q = lane >> 4;
  for (int i = lane; i < 16 * 64; i += 64) {
    int r = i >> 6, c = (i & 63) * 8;
    *(f16x8*)&hA[r][c] = *(const f16x8*)&h[(size_t)(mb*16 + r) * 512 + c];
    *(f16x8*)&Bw[r][c] = *(const f16x8*)&fw[(size_t)(nb*16 + r) * 512 + c];
  }
  __syncthreads();
  f32x4 acc = {};
#pragma unroll
  for (int kk = 0; kk < 16; ++kk) {
    f16x8 a = *(const f16x8*)&hA[l15][kk*32 + q*8];
    f16x8 b = *(const f16x8*)&Bw[l15][kk*32 + q*8];
    acc = __builtin_amdgcn_mfma_f32_16x16x32_f16(a, b, acc, 0, 0, 0);
  }
  float bv = (float)fb[nb*16 + l15];
  int md = *dmode;
#pragma unroll
  for (int r = 0; r < 4; ++r) {
    int idx = (mb*16 + q*4 + r) * 128 + nb*16 + l15;
    float val = acc[r] + bv;
    if (md) ((float*)outv)[idx] = val;
    else    ((u16*)outv)[idx]   = f2bf(val);
  }
}

// ---- final (fallback path): h from tagged buffer ----
__global__ __launch_bounds__(64) void k_final(const u32* __restrict__ h, const f16* __restrict__ fw,
                                              const f16* __restrict__ fb, void* __restrict__ outv,
                                              const int* __restrict__ dmode) {
  __shared__ f16 hA[16][520];
  __shared__ f16 Bw[16][520];
  const int mb = blockIdx.x & 3, nb = blockIdx.x >> 2;
  const int lane = threadIdx.x, l15 = lane & 15, q = lane >> 4;
  for (int i = lane; i < 16 * 128; i += 64) {
    int r = i >> 7, c = (i & 127) * 4;
    const u64* p = (const u64*)&h[(size_t)(mb*16 + r) * 512 + c];
    u64 v0 = al64(p), v1 = al64(p + 1);
    *(u32*)&hA[r][c]     = __builtin_amdgcn_perm((u32)(v0 >> 32), (u32)v0, 0x05040100u);
    *(u32*)&hA[r][c + 2] = __builtin_amdgcn_perm((u32)(v1 >> 32), (u32)v1, 0x05040100u);
  }
  for (int i = lane; i < 16 * 64; i += 64) {
    int r = i >> 6, c = (i & 63) * 8;
    *(f16x8*)&Bw[r][c] = *(const f16x8*)&fw[(size_t)(nb*16 + r) * 512 + c];
  }
  __syncthreads();
  f32x4 acc = {};
#pragma unroll
  for (int kk = 0; kk < 16; ++kk) {
    f16x8 a = *(const f16x8*)&hA[l15][kk*32 + q*8];
    f16x8 b = *(const f16x8*)&Bw[l15][kk*32 + q*8];
    acc = __builtin_amdgcn_mfma_f32_16x16x32_f16(a, b, acc, 0, 0, 0);
  }
  float bv = (float)fb[nb*16 + l15];
  int md = *dmode;
#pragma unroll
  for (int r = 0; r < 4; ++r) {
    int idx = (mb*16 + q*4 + r) * 128 + nb*16 + l15;
    float val = acc[r] + bv;
    if (md) ((float*)outv)[idx] = val;
    else    ((u16*)outv)[idx]   = f2bf(val);
  }
}

extern "C" void kernel_launch(void* const* d_in, const int* in_sizes, int n_in,
                              void* d_out, int out_size, void* d_ws, size_t ws_size,
                              hipStream_t stream) {
  if (ws_size < 88080384ull) {
    k_zero<<<32, 256, 0, stream>>>((u16*)d_out);
    return;
  }
  char* ws = (char*)d_ws;
  u32* hb1   = (u32*)(ws + 0);         // tagged h (fallback), 256 KB
  u32* hb2   = (u32*)(ws + 262144);    // tagged h (fallback), 256 KB
  int* dmode = (int*)(ws + 524288);
  f16* hlast2 = (f16*)(ws + 589824);   // 64 KB (big path)
  f16* Wx0f = (f16*)(ws + 1048576);
  f16* Uc0f = (f16*)(ws + 1179648);
  f16* Vh0f = (f16*)(ws + 1441792);
  f16* Wx1f = (f16*)(ws + 1966080);
  f16* Uc1f = (f16*)(ws + 2228224);
  f16* Vh1f = (f16*)(ws + 2490368);
  f16* fcwf = (f16*)(ws + 3014656);
  f16* bx0f = (f16*)(ws + 3145728);
  f16* bx1f = (f16*)(ws + 3146240);
  f16* fcbf = (f16*)(ws + 3146752);
  f16* x16  = (f16*)(ws + 4194304);    // 16 MB
  f16* A    = (f16*)(ws + 20971520);   // 32 MB: db1 | xp2+cb2
  f16* Xb   = (f16*)(ws + 54525952);   // 32 MB: xp1+cb1 | hs1 | db2
  f16* xp1 = Xb;
  f16* cb1 = Xb + 8388608;
  f16* db1 = A;                        // time-major [t][b][hid]
  f16* hs1 = Xb;
  f16* xp2 = A;
  f16* cb2 = A + 8388608;
  f16* db2 = Xb;                       // time-major

  // runtime capability check for the 148 KB-LDS scan (host query; graph-capture safe)
  int dev = 0, maxlds = 0;
  (void)hipGetDevice(&dev);
  (void)hipDeviceGetAttribute(&maxlds, hipDeviceAttributeMaxSharedMemoryPerBlock, dev);
  bool big = (maxlds >= SCAN4_LDS);
  if (big)
    (void)hipFuncSetAttribute((const void*)k_scan4,
                              hipFuncAttributeMaxDynamicSharedMemorySize, SCAN4_LDS);

  k_probe<<<1, 256, 0, stream>>>((const u16*)d_in[1], dmode);
  auto cvt = [&](const void* s, f16* d, int n) {
    int n8 = n / 8;
    k_cvt<<<dim3((n8 + 255) / 256), dim3(256), 0, stream>>>(s, d, n8, dmode);
  };
  cvt(d_in[0],  x16,  8388608);
  cvt(d_in[1],  Wx0f, 65536);
  cvt(d_in[2],  bx0f, 256);
  cvt(d_in[3],  Uc0f, 131072);
  cvt(d_in[4],  Vh0f, 262144);
  cvt(d_in[5],  Wx1f, 131072);
  cvt(d_in[6],  bx1f, 256);
  cvt(d_in[7],  Uc1f, 131072);
  cvt(d_in[8],  Vh1f, 262144);
  cvt(d_in[9],  fcwf, 65536);
  cvt(d_in[10], fcbf, 128);

  // layer 1
  k_gemm<true , false><<<dim3(2, 256), 256, 0, stream>>>(x16, Wx0f, bx0f, xp1, 32768, 256, 256);
  k_ema<<<512, 128, 0, stream>>>(xp1, cb1);
  k_gemm<false, true ><<<dim3(4, 256), 256, 0, stream>>>(cb1, Uc0f, nullptr, db1, 32768, 512, 256);
  if (big) k_scan4<<<4, 512, SCAN4_LDS, stream>>>(Vh0f, db1, hs1, nullptr);
  else     k_scan<<<8, 512, 0, stream>>>(Vh0f, db1, hb1, hs1);
  // layer 2
  k_gemm<true , false><<<dim3(2, 256), 256, 0, stream>>>(hs1, Wx1f, bx1f, xp2, 32768, 256, 512);
  k_ema<<<512, 128, 0, stream>>>(xp2, cb2);
  k_gemm<false, true ><<<dim3(4, 256), 256, 0, stream>>>(cb2, Uc1f, nullptr, db2, 32768, 512, 256);
  if (big) {
    k_scan4<<<4, 512, SCAN4_LDS, stream>>>(Vh1f, db2, nullptr, hlast2);
    k_final16<<<32, 64, 0, stream>>>(hlast2, fcwf, fcbf, d_out, dmode);
  } else {
    k_scan<<<8, 512, 0, stream>>>(Vh1f, db2, hb2, nullptr);
    k_final<<<32, 64, 0, stream>>>(hb2 + 64 * 512, fcwf, fcbf, d_out, dmode);
  }
}

// Round 9
// 3500.004 us; speedup vs baseline: 1.0032x; 1.0032x over previous
//
#include <hip/hip_runtime.h>

// SCRN: 2 layers of { xp = x@Wx^T+bx ; c_t = .05c+.95xp ; h_t = tanh(c@Uc^T + h@Vh^T) } + fc.
// EMA decay 0.05 -> 16-tap filter (parallel). d = c@Uc^T parallel GEMM (time-major).
// Recurrence: ZERO-EXCHANGE. 4 blocks, one per 16 batch rows, full 512 hid cols per block.
// 512 thr = 8 waves; per wave 64 out-cols: Vh 12 K-chunks in REGISTERS (192 VGPR) + 4 K-chunks
// in LDS (fragment-major, conflict-free); h[16][512] in LDS, 2 barriers/step.
// ROUND-9 FIX: __launch_bounds__(512, 2) — r8's plain (512) let the allocator cap at 128 VGPR
// and demote Bf to per-step L2 reloads (~384 KB/CU/step ≈ the whole 3.27us/step). 2 waves/EU
// declares the 256-VGPR budget the design needs. Fallback (small-LDS devices) = round-7 scan.

typedef _Float16 f16;
typedef _Float16 f16x8 __attribute__((ext_vector_type(8)));
typedef _Float16 f16x2 __attribute__((ext_vector_type(2)));
typedef float f32x4 __attribute__((ext_vector_type(4)));
typedef unsigned short u16;
typedef unsigned int u32;
typedef unsigned short u16x8 __attribute__((ext_vector_type(8)));
typedef unsigned long long u64;

#define DEV __device__ __forceinline__

constexpr int Tt = 512, HIDq = 512;
constexpr int SCAN4_LDS = 147712;   // hL 16*520*2 + BL 8*4*4*64*8*2

DEV float bf2f(u16 u) { unsigned v = ((unsigned)u) << 16; float f; __builtin_memcpy(&f, &v, 4); return f; }
DEV u16 f2bf(float f) { unsigned u; __builtin_memcpy(&u, &f, 4); u = (u + 0x7fffu + ((u >> 16) & 1u)) >> 16; return (u16)u; }
DEV float fast_tanh(float x) {
  x = fminf(30.f, fmaxf(-30.f, x));
  float e = exp2f(x * 2.885390081777927f);   // e^(2x)
  return (e - 1.f) / (e + 1.f);
}
DEV u64 al64(const u64* p) { return __hip_atomic_load(p, __ATOMIC_RELAXED, __HIP_MEMORY_SCOPE_AGENT); }
DEV void as32(u32* p, u32 v) { __hip_atomic_store(p, v, __ATOMIC_RELAXED, __HIP_MEMORY_SCOPE_AGENT); }

// ---- dtype probe: Wx0 entries bounded by 1/16; bf16 decode of f32 mantissa halves -> huge ----
__global__ void k_probe(const u16* __restrict__ w, int* __restrict__ dmode) {
  __shared__ int s;
  if (threadIdx.x == 0) s = 0;
  __syncthreads();
  int found = 0;
  for (int i = threadIdx.x; i < 8192; i += 256) {
    float v = bf2f(w[i]);
    if (fabsf(v) > 0.5f) found = 1;
  }
  if (found) atomicOr(&s, 1);
  __syncthreads();
  if (threadIdx.x == 0) *dmode = s;   // 0 = bf16 buffers, 1 = f32 buffers
}

// ---- convert n8*8 elements (bf16 or f32 per mode) -> fp16 ----
__global__ void k_cvt(const void* __restrict__ src, f16* __restrict__ dst, int n8,
                      const int* __restrict__ dmode) {
  int i = blockIdx.x * 256 + threadIdx.x;
  if (i >= n8) return;
  f16x8 o;
  if (*dmode) {
    const float4* s = (const float4*)src;
    float4 a = s[2*i], b = s[2*i+1];
    o[0]=(f16)a.x; o[1]=(f16)a.y; o[2]=(f16)a.z; o[3]=(f16)a.w;
    o[4]=(f16)b.x; o[5]=(f16)b.y; o[6]=(f16)b.z; o[7]=(f16)b.w;
  } else {
    u16x8 v = ((const u16x8*)src)[i];
#pragma unroll
    for (int j = 0; j < 8; ++j) o[j] = (f16)bf2f(v[j]);
  }
  ((f16x8*)dst)[i] = o;
}

__global__ void k_zero(u16* __restrict__ out) {  // diagnostic fallback (ws too small)
  out[blockIdx.x * 256 + threadIdx.x] = 0;
}

// ---- EMA c_t = 0.05 c_{t-1} + 0.95 xp_t ; 16-step warmup per 64-chunk ----
__global__ __launch_bounds__(128) void k_ema(const f16* __restrict__ xp, f16* __restrict__ c) {
  int b = blockIdx.x >> 3, chunk = blockIdx.x & 7;
  int t0 = chunk * 64;
  int ch = threadIdx.x;
  const f16x2* src = (const f16x2*)(xp + (size_t)b * Tt * 256) + ch;
  f16x2* dst = (f16x2*)(c + (size_t)b * Tt * 256) + ch;
  float c0 = 0.f, c1 = 0.f;
  int ts = (t0 >= 16) ? t0 - 16 : 0;
  for (int tt = ts; tt < t0 + 64; ++tt) {
    f16x2 v = src[(size_t)tt * 128];
    c0 = 0.05f * c0 + 0.95f * (float)v.x;
    c1 = 0.05f * c1 + 0.95f * (float)v.y;
    if (tt >= t0) { f16x2 o; o.x = (f16)c0; o.y = (f16)c1; dst[(size_t)tt * 128] = o; }
  }
}

// ---- GEMM: C = A[M,K] @ B[N,K]^T (+bias). TD: store C time-major (row b*512+t -> t*64+b) ----
template<bool HAS_BIAS, bool TD>
__global__ __launch_bounds__(256) void k_gemm(const f16* __restrict__ A, const f16* __restrict__ Bm,
                                              const f16* __restrict__ bias, f16* __restrict__ C,
                                              int M, int N, int K) {
  __shared__ f16 As[128][40];
  __shared__ f16 Bs[128][40];
  const int tid = threadIdx.x, lane = tid & 63, wv = tid >> 6;
  const int l15 = lane & 15, q = lane >> 4;
  const int wm = wv >> 1, wn = wv & 1;
  const int m0 = blockIdx.y * 128, n0 = blockIdx.x * 128;
  const int srow = tid >> 1, sseg = tid & 1;
  f32x4 acc[4][4] = {};
  const f16* ga = A  + (size_t)(m0 + srow) * K + sseg * 16;
  const f16* gb = Bm + (size_t)(n0 + srow) * K + sseg * 16;
  for (int k0 = 0; k0 < K; k0 += 32) {
    f16x8 a0 = *(const f16x8*)(ga + k0);
    f16x8 a1 = *(const f16x8*)(ga + k0 + 8);
    f16x8 b0 = *(const f16x8*)(gb + k0);
    f16x8 b1 = *(const f16x8*)(gb + k0 + 8);
    __syncthreads();
    *(f16x8*)&As[srow][sseg*16]     = a0;
    *(f16x8*)&As[srow][sseg*16 + 8] = a1;
    *(f16x8*)&Bs[srow][sseg*16]     = b0;
    *(f16x8*)&Bs[srow][sseg*16 + 8] = b1;
    __syncthreads();
    f16x8 af[4], bf[4];
#pragma unroll
    for (int i = 0; i < 4; ++i) af[i] = *(const f16x8*)&As[wm*64 + i*16 + l15][q*8];
#pragma unroll
    for (int i = 0; i < 4; ++i) bf[i] = *(const f16x8*)&Bs[wn*64 + i*16 + l15][q*8];
#pragma unroll
    for (int i = 0; i < 4; ++i)
#pragma unroll
      for (int j = 0; j < 4; ++j)
        acc[i][j] = __builtin_amdgcn_mfma_f32_16x16x32_f16(af[i], bf[j], acc[i][j], 0, 0, 0);
  }
#pragma unroll
  for (int j = 0; j < 4; ++j) {
    int col = n0 + wn*64 + j*16 + l15;
    float bv = HAS_BIAS ? (float)bias[col] : 0.f;
#pragma unroll
    for (int i = 0; i < 4; ++i)
#pragma unroll
      for (int r = 0; r < 4; ++r) {
        int row = m0 + wm*64 + i*16 + q*4 + r;
        size_t orow = TD ? (size_t)((row & 511) * 64 + (row >> 9)) : (size_t)row;
        C[orow * N + col] = (f16)(acc[i][j][r] + bv);
      }
  }
}

// ---- BIG-LDS scan: zero-exchange. 4 blocks (16 batch rows each), 512 thr = 8 waves. ----
// Wave w: out cols 64w..+63 (4 tiles). Vh: chunks 0..11 in regs Bf[12][4]; chunks 12..15 in LDS
// fragment-major (lane-consecutive 16B => conflict-free). hL[16][520] single buffer.
// launch_bounds(512,2): declare 2 waves/EU so the allocator gets the full 256-VGPR budget.
__global__ __launch_bounds__(512, 2) void k_scan4(const f16* __restrict__ Vh,
                                                  const f16* __restrict__ d2,
                                                  f16* __restrict__ hs_out,
                                                  f16* __restrict__ hlast) {
  extern __shared__ f16 smem[];
  f16* hL = smem;                  // 16 x 520
  f16* BL = smem + 16 * 520;       // ((w*4+c)*4+j)*64+lane, 8 f16 each
  const int g = blockIdx.x;
  const int tid = threadIdx.x, w = tid >> 6, lane = tid & 63;
  const int l15 = lane & 15, q = lane >> 4;

  // stage Vh: regs (chunks 0..11) + LDS (chunks 12..15); single hoisted base pointer
  const f16* vbase = Vh + (size_t)(64*w + l15) * HIDq + q*8;
  f16x8 Bf[12][4];
#pragma unroll
  for (int kk = 0; kk < 12; ++kk)
#pragma unroll
    for (int j = 0; j < 4; ++j)
      Bf[kk][j] = *(const f16x8*)(vbase + (size_t)(16*j) * HIDq + kk*32);
#pragma unroll
  for (int c = 0; c < 4; ++c)
#pragma unroll
    for (int j = 0; j < 4; ++j) {
      f16x8 v = *(const f16x8*)(vbase + (size_t)(16*j) * HIDq + (12+c)*32);
      *(f16x8*)&BL[(size_t)(((w*4 + c)*4 + j)*64 + lane) * 8] = v;
    }
  // h_{-1} = 0
  for (int i = tid; i < 1024; i += 512) {
    int r = i >> 6, cc = (i & 63) * 8;
    f16x8 z = {};
    *(f16x8*)&hL[r*520 + cc] = z;
  }
  // d_0 prefetch (packed f16: 8 VGPRs, halves register pressure vs f32)
  const f16* dbase = d2 + (size_t)(16*g + q*4) * HIDq + 64*w + l15;
  f16 dv[4][4];
#pragma unroll
  for (int j = 0; j < 4; ++j)
#pragma unroll
    for (int r = 0; r < 4; ++r)
      dv[j][r] = dbase[(size_t)r * HIDq + j*16];
  __syncthreads();

  for (int t = 0; t < Tt; ++t) {
    // MFMA: 4 col-tiles x 16 K-chunks; A from hL, B from regs/LDS
    f32x4 acc[4] = {};
#pragma unroll
    for (int kk = 0; kk < 16; ++kk) {
      f16x8 a = *(const f16x8*)&hL[l15*520 + kk*32 + q*8];
      if (kk < 12) {
#pragma unroll
        for (int j = 0; j < 4; ++j)
          acc[j] = __builtin_amdgcn_mfma_f32_16x16x32_f16(a, Bf[kk][j], acc[j], 0, 0, 0);
      } else {
        const int c = kk - 12;
#pragma unroll
        for (int j = 0; j < 4; ++j) {
          f16x8 bl = *(const f16x8*)&BL[(size_t)(((w*4 + c)*4 + j)*64 + lane) * 8];
          acc[j] = __builtin_amdgcn_mfma_f32_16x16x32_f16(a, bl, acc[j], 0, 0, 0);
        }
      }
    }
    __syncthreads();   // all A-reads of h_{t-1} done
    // epilogue: tanh -> write h_t into hL (row=q*4+r, col=64w+16j+l15)
#pragma unroll
    for (int j = 0; j < 4; ++j)
#pragma unroll
      for (int r = 0; r < 4; ++r) {
        float z = acc[j][r] + (float)dv[j][r];
        hL[(q*4 + r)*520 + 64*w + 16*j + l15] = (f16)fast_tanh(z);
      }
    __syncthreads();   // h_t complete
    // hs_out copy (coalesced b128 from LDS), hlast at t=511
    if (hs_out) {
#pragma unroll
      for (int i = tid; i < 1024; i += 512) {
        int r = i >> 6, cc = (i & 63) * 8;
        *(f16x8*)&hs_out[((size_t)(16*g + r) * Tt + t) * HIDq + cc] =
            *(const f16x8*)&hL[r*520 + cc];
      }
    }
    if (hlast && t == Tt - 1) {
#pragma unroll
      for (int i = tid; i < 1024; i += 512) {
        int r = i >> 6, cc = (i & 63) * 8;
        *(f16x8*)&hlast[(size_t)(16*g + r) * HIDq + cc] = *(const f16x8*)&hL[r*520 + cc];
      }
    }
    // d prefetch t+1
    if (t < Tt - 1) {
      const f16* dt = dbase + (size_t)(t+1) * 64 * HIDq;
#pragma unroll
      for (int j = 0; j < 4; ++j)
#pragma unroll
        for (int r = 0; r < 4; ++r)
          dv[j][r] = dt[(size_t)r * HIDq + j*16];
    }
  }
}

// ---- FALLBACK scan (round-7, verbatim): community-2 tagged LLC exchange ----
__global__ __launch_bounds__(512, 2) void k_scan(const f16* __restrict__ Vh,
                                                 const f16* __restrict__ d2,
                                                 u32* __restrict__ htag,
                                                 f16* __restrict__ hs_out) {
  __shared__ f16 hL[2][16][520];
  const int bid = blockIdx.x, hf = bid & 1, g = bid >> 1;
  const int tid = threadIdx.x, w = tid >> 6, lane = tid & 63;
  const int l15 = lane & 15, q = lane >> 4;
  const int colbase = 256*hf + 32*w;
  f16x8 Bf[2][16];
#pragma unroll
  for (int j = 0; j < 2; ++j)
#pragma unroll
    for (int kk = 0; kk < 16; ++kk)
      Bf[j][kk] = *(const f16x8*)&Vh[(size_t)(colbase + 16*j + l15) * HIDq + kk*32 + q*8];
  for (int i = tid; i < 1024; i += 512) {
    int r = i >> 6, c = (i & 63) * 8;
    f16x8 z = {};
    *(f16x8*)&hL[0][r][c] = z;
  }
  float dv[2][4];
#pragma unroll
  for (int j = 0; j < 2; ++j)
#pragma unroll
    for (int r = 0; r < 4; ++r)
      dv[j][r] = (float)d2[((size_t)0*64 + 16*g + q*4 + r) * HIDq + colbase + 16*j + l15];
  __syncthreads();
  const int irow = tid >> 5, ic8 = (tid & 31) * 8;
  const int pcol = 256*(hf ^ 1) + ic8;
  for (int t = 0; t < Tt; ++t) {
    const int rb = t & 1, wb = rb ^ 1, slot = t & 1;
    if (hs_out && t > 0) {
#pragma unroll
      for (int c = tid; c < 1024; c += 512) {
        int r = c >> 6, cc = (c & 63) * 8;
        *(f16x8*)&hs_out[((size_t)(16*g + r) * Tt + (t-1)) * HIDq + cc] =
            *(const f16x8*)&hL[rb][r][cc];
      }
    }
    f32x4 a00 = {}, a01 = {}, a10 = {}, a11 = {};
#pragma unroll
    for (int kk = 0; kk < 16; ++kk) {
      f16x8 a = *(const f16x8*)&hL[rb][l15][kk*32 + q*8];
      if (kk & 1) {
        a01 = __builtin_amdgcn_mfma_f32_16x16x32_f16(a, Bf[0][kk], a01, 0, 0, 0);
        a11 = __builtin_amdgcn_mfma_f32_16x16x32_f16(a, Bf[1][kk], a11, 0, 0, 0);
      } else {
        a00 = __builtin_amdgcn_mfma_f32_16x16x32_f16(a, Bf[0][kk], a00, 0, 0, 0);
        a10 = __builtin_amdgcn_mfma_f32_16x16x32_f16(a, Bf[1][kk], a10, 0, 0, 0);
      }
    }
    const u32 tagw = (u32)(t + 1) << 16;
    u16 hbits[2][4];
#pragma unroll
    for (int j = 0; j < 2; ++j) {
      f32x4 s = j ? (a10 + a11) : (a00 + a01);
#pragma unroll
      for (int r = 0; r < 4; ++r) {
        float z = s[r] + dv[j][r];
        union { f16 h; u16 u; } cv; cv.h = (f16)fast_tanh(z);
        hbits[j][r] = cv.u;
        as32(&htag[(size_t)(slot*64 + 16*g + q*4 + r) * HIDq + colbase + 16*j + l15],
             tagw | (u32)cv.u);
      }
    }
#pragma unroll
    for (int j = 0; j < 2; ++j)
#pragma unroll
      for (int r = 0; r < 4; ++r) {
        union { u16 u; f16 h; } cv; cv.u = hbits[j][r];
        hL[wb][q*4 + r][colbase + 16*j + l15] = cv.h;
      }
    if (t < Tt - 1) {
#pragma unroll
      for (int j = 0; j < 2; ++j)
#pragma unroll
        for (int r = 0; r < 4; ++r)
          dv[j][r] = (float)d2[((size_t)(t+1)*64 + 16*g + q*4 + r) * HIDq + colbase + 16*j + l15];
    }
    {
      const u64* pp = (const u64*)&htag[(size_t)(slot*64 + 16*g + irow) * HIDq] + pcol/2;
      u64 v[4];
#pragma unroll
      for (int jj = 0; jj < 4; ++jj) v[jj] = al64(pp + jj);
      for (;;) {
        u32 bad = 0;
#pragma unroll
        for (int jj = 0; jj < 4; ++jj)
          bad |= ((u32)v[jj] ^ tagw) | ((u32)(v[jj] >> 32) ^ tagw);
        if ((bad & 0xFFFF0000u) == 0) break;
#pragma unroll
        for (int jj = 0; jj < 4; ++jj) v[jj] = al64(pp + jj);
      }
      union { u32 wd[4]; f16x8 vv; } fr;
#pragma unroll
      for (int jj = 0; jj < 4; ++jj)
        fr.wd[jj] = __builtin_amdgcn_perm((u32)(v[jj] >> 32), (u32)v[jj], 0x05040100u);
      *(f16x8*)&hL[wb][irow][pcol] = fr.vv;
    }
    __syncthreads();
  }
  if (hs_out) {
#pragma unroll
    for (int c = tid; c < 1024; c += 512) {
      int r = c >> 6, cc = (c & 63) * 8;
      *(f16x8*)&hs_out[((size_t)(16*g + r) * Tt + (Tt-1)) * HIDq + cc] =
          *(const f16x8*)&hL[0][r][cc];
    }
  }
}

// ---- final (big path): out = h_last[64,512] @ fc_w^T + fc_b; h plain f16 ----
__global__ __launch_bounds__(64) void k_final16(const f16* __restrict__ h, const f16* __restrict__ fw,
                                                const f16* __restrict__ fb, void* __restrict__ outv,
                                                const int* __restrict__ dmode) {
  __shared__ f16 hA[16][520];
  __shared__ f16 Bw[16][520];
  const int mb = blockIdx.x & 3, nb = blockIdx.x >> 2;
  const int lane = threadIdx.x, l15 = lane & 15, q = lane >> 4;
  for (int i = lane; i < 16 * 64; i += 64) {
    int r = i >> 6, c = (i & 63) * 8;
    *(f16x8*)&hA[r][c] = *(const f16x8*)&h[(size_t)(mb*16 + r) * 512 + c];
    *(f16x8*)&Bw[r][c] = *(const f16x8*)&fw[(size_t)(nb*16 + r) * 512 + c];
  }
  __syncthreads();
  f32x4 acc = {};
#pragma unroll
  for (int kk = 0; kk < 16; ++kk) {
    f16x8 a = *(const f16x8*)&hA[l15][kk*32 + q*8];
    f16x8 b = *(const f16x8*)&Bw[l15][kk*32 + q*8];
    acc = __builtin_amdgcn_mfma_f32_16x16x32_f16(a, b, acc, 0, 0, 0);
  }
  float bv = (float)fb[nb*16 + l15];
  int md = *dmode;
#pragma unroll
  for (int r = 0; r < 4; ++r) {
    int idx = (mb*16 + q*4 + r) * 128 + nb*16 + l15;
    float val = acc[r] + bv;
    if (md) ((float*)outv)[idx] = val;
    else    ((u16*)outv)[idx]   = f2bf(val);
  }
}

// ---- final (fallback path): h from tagged buffer ----
__global__ __launch_bounds__(64) void k_final(const u32* __restrict__ h, const f16* __restrict__ fw,
                                              const f16* __restrict__ fb, void* __restrict__ outv,
                                              const int* __restrict__ dmode) {
  __shared__ f16 hA[16][520];
  __shared__ f16 Bw[16][520];
  const int mb = blockIdx.x & 3, nb = blockIdx.x >> 2;
  const int lane = threadIdx.x, l15 = lane & 15, q = lane >> 4;
  for (int i = lane; i < 16 * 128; i += 64) {
    int r = i >> 7, c = (i & 127) * 4;
    const u64* p = (const u64*)&h[(size_t)(mb*16 + r) * 512 + c];
    u64 v0 = al64(p), v1 = al64(p + 1);
    *(u32*)&hA[r][c]     = __builtin_amdgcn_perm((u32)(v0 >> 32), (u32)v0, 0x05040100u);
    *(u32*)&hA[r][c + 2] = __builtin_amdgcn_perm((u32)(v1 >> 32), (u32)v1, 0x05040100u);
  }
  for (int i = lane; i < 16 * 64; i += 64) {
    int r = i >> 6, c = (i & 63) * 8;
    *(f16x8*)&Bw[r][c] = *(const f16x8*)&fw[(size_t)(nb*16 + r) * 512 + c];
  }
  __syncthreads();
  f32x4 acc = {};
#pragma unroll
  for (int kk = 0; kk < 16; ++kk) {
    f16x8 a = *(const f16x8*)&hA[l15][kk*32 + q*8];
    f16x8 b = *(const f16x8*)&Bw[l15][kk*32 + q*8];
    acc = __builtin_amdgcn_mfma_f32_16x16x32_f16(a, b, acc, 0, 0, 0);
  }
  float bv = (float)fb[nb*16 + l15];
  int md = *dmode;
#pragma unroll
  for (int r = 0; r < 4; ++r) {
    int idx = (mb*16 + q*4 + r) * 128 + nb*16 + l15;
    float val = acc[r] + bv;
    if (md) ((float*)outv)[idx] = val;
    else    ((u16*)outv)[idx]   = f2bf(val);
  }
}

extern "C" void kernel_launch(void* const* d_in, const int* in_sizes, int n_in,
                              void* d_out, int out_size, void* d_ws, size_t ws_size,
                              hipStream_t stream) {
  if (ws_size < 88080384ull) {
    k_zero<<<32, 256, 0, stream>>>((u16*)d_out);
    return;
  }
  char* ws = (char*)d_ws;
  u32* hb1   = (u32*)(ws + 0);         // tagged h (fallback), 256 KB
  u32* hb2   = (u32*)(ws + 262144);    // tagged h (fallback), 256 KB
  int* dmode = (int*)(ws + 524288);
  f16* hlast2 = (f16*)(ws + 589824);   // 64 KB (big path)
  f16* Wx0f = (f16*)(ws + 1048576);
  f16* Uc0f = (f16*)(ws + 1179648);
  f16* Vh0f = (f16*)(ws + 1441792);
  f16* Wx1f = (f16*)(ws + 1966080);
  f16* Uc1f = (f16*)(ws + 2228224);
  f16* Vh1f = (f16*)(ws + 2490368);
  f16* fcwf = (f16*)(ws + 3014656);
  f16* bx0f = (f16*)(ws + 3145728);
  f16* bx1f = (f16*)(ws + 3146240);
  f16* fcbf = (f16*)(ws + 3146752);
  f16* x16  = (f16*)(ws + 4194304);    // 16 MB
  f16* A    = (f16*)(ws + 20971520);   // 32 MB: db1 | xp2+cb2
  f16* Xb   = (f16*)(ws + 54525952);   // 32 MB: xp1+cb1 | hs1 | db2
  f16* xp1 = Xb;
  f16* cb1 = Xb + 8388608;
  f16* db1 = A;                        // time-major [t][b][hid]
  f16* hs1 = Xb;
  f16* xp2 = A;
  f16* cb2 = A + 8388608;
  f16* db2 = Xb;                       // time-major

  // runtime capability check for the 148 KB-LDS scan (host query; graph-capture safe)
  int dev = 0, maxlds = 0;
  (void)hipGetDevice(&dev);
  (void)hipDeviceGetAttribute(&maxlds, hipDeviceAttributeMaxSharedMemoryPerBlock, dev);
  bool big = (maxlds >= SCAN4_LDS);
  if (big)
    (void)hipFuncSetAttribute((const void*)k_scan4,
                              hipFuncAttributeMaxDynamicSharedMemorySize, SCAN4_LDS);

  k_probe<<<1, 256, 0, stream>>>((const u16*)d_in[1], dmode);
  auto cvt = [&](const void* s, f16* d, int n) {
    int n8 = n / 8;
    k_cvt<<<dim3((n8 + 255) / 256), dim3(256), 0, stream>>>(s, d, n8, dmode);
  };
  cvt(d_in[0],  x16,  8388608);
  cvt(d_in[1],  Wx0f, 65536);
  cvt(d_in[2],  bx0f, 256);
  cvt(d_in[3],  Uc0f, 131072);
  cvt(d_in[4],  Vh0f, 262144);
  cvt(d_in[5],  Wx1f, 131072);
  cvt(d_in[6],  bx1f, 256);
  cvt(d_in[7],  Uc1f, 131072);
  cvt(d_in[8],  Vh1f, 262144);
  cvt(d_in[9],  fcwf, 65536);
  cvt(d_in[10], fcbf, 128);

  // layer 1
  k_gemm<true , false><<<dim3(2, 256), 256, 0, stream>>>(x16, Wx0f, bx0f, xp1, 32768, 256, 256);
  k_ema<<<512, 128, 0, stream>>>(xp1, cb1);
  k_gemm<false, true ><<<dim3(4, 256), 256, 0, stream>>>(cb1, Uc0f, nullptr, db1, 32768, 512, 256);
  if (big) k_scan4<<<4, 512, SCAN4_LDS, stream>>>(Vh0f, db1, hs1, nullptr);
  else     k_scan<<<8, 512, 0, stream>>>(Vh0f, db1, hb1, hs1);
  // layer 2
  k_gemm<true , false><<<dim3(2, 256), 256, 0, stream>>>(hs1, Wx1f, bx1f, xp2, 32768, 256, 512);
  k_ema<<<512, 128, 0, stream>>>(xp2, cb2);
  k_gemm<false, true ><<<dim3(4, 256), 256, 0, stream>>>(cb2, Uc1f, nullptr, db2, 32768, 512, 256);
  if (big) {
    k_scan4<<<4, 512, SCAN4_LDS, stream>>>(Vh1f, db2, nullptr, hlast2);
    k_final16<<<32, 64, 0, stream>>>(hlast2, fcwf, fcbf, d_out, dmode);
  } else {
    k_scan<<<8, 512, 0, stream>>>(Vh1f, db2, hb2, nullptr);
    k_final<<<32, 64, 0, stream>>>(hb2 + 64 * 512, fcwf, fcbf, d_out, dmode);
  }
}

// Round 10
// 3396.830 us; speedup vs baseline: 1.0336x; 1.0304x over previous
//
#include <hip/hip_runtime.h>

// SCRN: 2 layers of { xp = x@Wx^T+bx ; c_t = .05c+.95xp ; h_t = tanh(c@Uc^T + h@Vh^T) } + fc.
// EMA decay 0.05 -> 16-tap filter (parallel). d = c@Uc^T parallel GEMM (time-major).
// Recurrence: ZERO-EXCHANGE. 4 blocks, one per 16 batch rows, full 512 hid cols per block.
// 512 thr = 8 waves; per wave 64 out-cols: Vh 12 K-chunks in REGISTERS (192 VGPR) + 4 K-chunks
// in LDS (fragment-major, conflict-free); h[16][512] in LDS, 2 barriers/step.
// ROUND-10 FIX: r9's launch_bounds(512,2) did NOT move the allocator off 128 VGPR — the
// occupancy model (blind to the 147KB dynamic LDS) targeted 2 blocks/CU and rematerialized Bf
// from L2 every step (384 KB/CU/step = the whole 3.2us/step). Now: amdgpu_waves_per_eu(2,2)
// pins the occupancy TARGET, and empty inline-asm ("+v") pins Bf values so remat is impossible.

typedef _Float16 f16;
typedef _Float16 f16x8 __attribute__((ext_vector_type(8)));
typedef _Float16 f16x2 __attribute__((ext_vector_type(2)));
typedef float f32x4 __attribute__((ext_vector_type(4)));
typedef unsigned short u16;
typedef unsigned int u32;
typedef unsigned short u16x8 __attribute__((ext_vector_type(8)));
typedef unsigned long long u64;

#define DEV __device__ __forceinline__

constexpr int Tt = 512, HIDq = 512;
constexpr int SCAN4_LDS = 147712;   // hL 16*520*2 + BL 8*4*4*64*8*2

DEV float bf2f(u16 u) { unsigned v = ((unsigned)u) << 16; float f; __builtin_memcpy(&f, &v, 4); return f; }
DEV u16 f2bf(float f) { unsigned u; __builtin_memcpy(&u, &f, 4); u = (u + 0x7fffu + ((u >> 16) & 1u)) >> 16; return (u16)u; }
DEV float fast_tanh(float x) {
  x = fminf(30.f, fmaxf(-30.f, x));
  float e = exp2f(x * 2.885390081777927f);   // e^(2x)
  return (e - 1.f) / (e + 1.f);
}
DEV u64 al64(const u64* p) { return __hip_atomic_load(p, __ATOMIC_RELAXED, __HIP_MEMORY_SCOPE_AGENT); }
DEV void as32(u32* p, u32 v) { __hip_atomic_store(p, v, __ATOMIC_RELAXED, __HIP_MEMORY_SCOPE_AGENT); }

// ---- dtype probe: Wx0 entries bounded by 1/16; bf16 decode of f32 mantissa halves -> huge ----
__global__ void k_probe(const u16* __restrict__ w, int* __restrict__ dmode) {
  __shared__ int s;
  if (threadIdx.x == 0) s = 0;
  __syncthreads();
  int found = 0;
  for (int i = threadIdx.x; i < 8192; i += 256) {
    float v = bf2f(w[i]);
    if (fabsf(v) > 0.5f) found = 1;
  }
  if (found) atomicOr(&s, 1);
  __syncthreads();
  if (threadIdx.x == 0) *dmode = s;   // 0 = bf16 buffers, 1 = f32 buffers
}

// ---- convert n8*8 elements (bf16 or f32 per mode) -> fp16 ----
__global__ void k_cvt(const void* __restrict__ src, f16* __restrict__ dst, int n8,
                      const int* __restrict__ dmode) {
  int i = blockIdx.x * 256 + threadIdx.x;
  if (i >= n8) return;
  f16x8 o;
  if (*dmode) {
    const float4* s = (const float4*)src;
    float4 a = s[2*i], b = s[2*i+1];
    o[0]=(f16)a.x; o[1]=(f16)a.y; o[2]=(f16)a.z; o[3]=(f16)a.w;
    o[4]=(f16)b.x; o[5]=(f16)b.y; o[6]=(f16)b.z; o[7]=(f16)b.w;
  } else {
    u16x8 v = ((const u16x8*)src)[i];
#pragma unroll
    for (int j = 0; j < 8; ++j) o[j] = (f16)bf2f(v[j]);
  }
  ((f16x8*)dst)[i] = o;
}

__global__ void k_zero(u16* __restrict__ out) {  // diagnostic fallback (ws too small)
  out[blockIdx.x * 256 + threadIdx.x] = 0;
}

// ---- EMA c_t = 0.05 c_{t-1} + 0.95 xp_t ; 16-step warmup per 64-chunk ----
__global__ __launch_bounds__(128) void k_ema(const f16* __restrict__ xp, f16* __restrict__ c) {
  int b = blockIdx.x >> 3, chunk = blockIdx.x & 7;
  int t0 = chunk * 64;
  int ch = threadIdx.x;
  const f16x2* src = (const f16x2*)(xp + (size_t)b * Tt * 256) + ch;
  f16x2* dst = (f16x2*)(c + (size_t)b * Tt * 256) + ch;
  float c0 = 0.f, c1 = 0.f;
  int ts = (t0 >= 16) ? t0 - 16 : 0;
  for (int tt = ts; tt < t0 + 64; ++tt) {
    f16x2 v = src[(size_t)tt * 128];
    c0 = 0.05f * c0 + 0.95f * (float)v.x;
    c1 = 0.05f * c1 + 0.95f * (float)v.y;
    if (tt >= t0) { f16x2 o; o.x = (f16)c0; o.y = (f16)c1; dst[(size_t)tt * 128] = o; }
  }
}

// ---- GEMM: C = A[M,K] @ B[N,K]^T (+bias). TD: store C time-major (row b*512+t -> t*64+b) ----
template<bool HAS_BIAS, bool TD>
__global__ __launch_bounds__(256) void k_gemm(const f16* __restrict__ A, const f16* __restrict__ Bm,
                                              const f16* __restrict__ bias, f16* __restrict__ C,
                                              int M, int N, int K) {
  __shared__ f16 As[128][40];
  __shared__ f16 Bs[128][40];
  const int tid = threadIdx.x, lane = tid & 63, wv = tid >> 6;
  const int l15 = lane & 15, q = lane >> 4;
  const int wm = wv >> 1, wn = wv & 1;
  const int m0 = blockIdx.y * 128, n0 = blockIdx.x * 128;
  const int srow = tid >> 1, sseg = tid & 1;
  f32x4 acc[4][4] = {};
  const f16* ga = A  + (size_t)(m0 + srow) * K + sseg * 16;
  const f16* gb = Bm + (size_t)(n0 + srow) * K + sseg * 16;
  for (int k0 = 0; k0 < K; k0 += 32) {
    f16x8 a0 = *(const f16x8*)(ga + k0);
    f16x8 a1 = *(const f16x8*)(ga + k0 + 8);
    f16x8 b0 = *(const f16x8*)(gb + k0);
    f16x8 b1 = *(const f16x8*)(gb + k0 + 8);
    __syncthreads();
    *(f16x8*)&As[srow][sseg*16]     = a0;
    *(f16x8*)&As[srow][sseg*16 + 8] = a1;
    *(f16x8*)&Bs[srow][sseg*16]     = b0;
    *(f16x8*)&Bs[srow][sseg*16 + 8] = b1;
    __syncthreads();
    f16x8 af[4], bf[4];
#pragma unroll
    for (int i = 0; i < 4; ++i) af[i] = *(const f16x8*)&As[wm*64 + i*16 + l15][q*8];
#pragma unroll
    for (int i = 0; i < 4; ++i) bf[i] = *(const f16x8*)&Bs[wn*64 + i*16 + l15][q*8];
#pragma unroll
    for (int i = 0; i < 4; ++i)
#pragma unroll
      for (int j = 0; j < 4; ++j)
        acc[i][j] = __builtin_amdgcn_mfma_f32_16x16x32_f16(af[i], bf[j], acc[i][j], 0, 0, 0);
  }
#pragma unroll
  for (int j = 0; j < 4; ++j) {
    int col = n0 + wn*64 + j*16 + l15;
    float bv = HAS_BIAS ? (float)bias[col] : 0.f;
#pragma unroll
    for (int i = 0; i < 4; ++i)
#pragma unroll
      for (int r = 0; r < 4; ++r) {
        int row = m0 + wm*64 + i*16 + q*4 + r;
        size_t orow = TD ? (size_t)((row & 511) * 64 + (row >> 9)) : (size_t)row;
        C[orow * N + col] = (f16)(acc[i][j][r] + bv);
      }
  }
}

// ---- BIG-LDS scan: zero-exchange. 4 blocks (16 batch rows each), 512 thr = 8 waves. ----
// Wave w: out cols 64w..+63 (4 tiles). Vh: chunks 0..11 in regs Bf[12][4]; chunks 12..15 in LDS
// fragment-major (lane-consecutive 16B => conflict-free). hL[16][520] single buffer.
// waves_per_eu(2,2): pin occupancy target = 2 waves/EU -> 256-VGPR budget; inline-asm pins Bf.
__global__ __attribute__((amdgpu_flat_work_group_size(512, 512), amdgpu_waves_per_eu(2, 2)))
void k_scan4(const f16* __restrict__ Vh,
             const f16* __restrict__ d2,
             f16* __restrict__ hs_out,
             f16* __restrict__ hlast) {
  extern __shared__ f16 smem[];
  f16* hL = smem;                  // 16 x 520
  f16* BL = smem + 16 * 520;       // ((w*4+c)*4+j)*64+lane, 8 f16 each
  const int g = blockIdx.x;
  const int tid = threadIdx.x, w = tid >> 6, lane = tid & 63;
  const int l15 = lane & 15, q = lane >> 4;

  // stage Vh: regs (chunks 0..11) + LDS (chunks 12..15); single hoisted base pointer
  const f16* vbase = Vh + (size_t)(64*w + l15) * HIDq + q*8;
  f16x8 Bf[12][4];
#pragma unroll
  for (int kk = 0; kk < 12; ++kk)
#pragma unroll
    for (int j = 0; j < 4; ++j) {
      Bf[kk][j] = *(const f16x8*)(vbase + (size_t)(16*j) * HIDq + kk*32);
      asm volatile("" : "+v"(Bf[kk][j]));   // opaque: forbid rematerialization from global
    }
#pragma unroll
  for (int c = 0; c < 4; ++c)
#pragma unroll
    for (int j = 0; j < 4; ++j) {
      f16x8 v = *(const f16x8*)(vbase + (size_t)(16*j) * HIDq + (12+c)*32);
      *(f16x8*)&BL[(size_t)(((w*4 + c)*4 + j)*64 + lane) * 8] = v;
    }
  // h_{-1} = 0
  for (int i = tid; i < 1024; i += 512) {
    int r = i >> 6, cc = (i & 63) * 8;
    f16x8 z = {};
    *(f16x8*)&hL[r*520 + cc] = z;
  }
  // d_0 prefetch (packed f16: 8 VGPRs)
  const f16* dbase = d2 + (size_t)(16*g + q*4) * HIDq + 64*w + l15;
  f16 dv[4][4];
#pragma unroll
  for (int j = 0; j < 4; ++j)
#pragma unroll
    for (int r = 0; r < 4; ++r)
      dv[j][r] = dbase[(size_t)r * HIDq + j*16];
  __syncthreads();

  for (int t = 0; t < Tt; ++t) {
    // MFMA: 4 col-tiles x 16 K-chunks; A from hL, B from regs/LDS
    f32x4 acc[4] = {};
#pragma unroll
    for (int kk = 0; kk < 16; ++kk) {
      f16x8 a = *(const f16x8*)&hL[l15*520 + kk*32 + q*8];
      if (kk < 12) {
#pragma unroll
        for (int j = 0; j < 4; ++j)
          acc[j] = __builtin_amdgcn_mfma_f32_16x16x32_f16(a, Bf[kk][j], acc[j], 0, 0, 0);
      } else {
        const int c = kk - 12;
#pragma unroll
        for (int j = 0; j < 4; ++j) {
          f16x8 bl = *(const f16x8*)&BL[(size_t)(((w*4 + c)*4 + j)*64 + lane) * 8];
          acc[j] = __builtin_amdgcn_mfma_f32_16x16x32_f16(a, bl, acc[j], 0, 0, 0);
        }
      }
    }
    __syncthreads();   // all A-reads of h_{t-1} done
    // epilogue: tanh -> write h_t into hL (row=q*4+r, col=64w+16j+l15)
#pragma unroll
    for (int j = 0; j < 4; ++j)
#pragma unroll
      for (int r = 0; r < 4; ++r) {
        float z = acc[j][r] + (float)dv[j][r];
        hL[(q*4 + r)*520 + 64*w + 16*j + l15] = (f16)fast_tanh(z);
      }
    __syncthreads();   // h_t complete
    // hs_out copy (coalesced b128 from LDS), hlast at t=511
    if (hs_out) {
#pragma unroll
      for (int i = tid; i < 1024; i += 512) {
        int r = i >> 6, cc = (i & 63) * 8;
        *(f16x8*)&hs_out[((size_t)(16*g + r) * Tt + t) * HIDq + cc] =
            *(const f16x8*)&hL[r*520 + cc];
      }
    }
    if (hlast && t == Tt - 1) {
#pragma unroll
      for (int i = tid; i < 1024; i += 512) {
        int r = i >> 6, cc = (i & 63) * 8;
        *(f16x8*)&hlast[(size_t)(16*g + r) * HIDq + cc] = *(const f16x8*)&hL[r*520 + cc];
      }
    }
    // d prefetch t+1
    if (t < Tt - 1) {
      const f16* dt = dbase + (size_t)(t+1) * 64 * HIDq;
#pragma unroll
      for (int j = 0; j < 4; ++j)
#pragma unroll
        for (int r = 0; r < 4; ++r)
          dv[j][r] = dt[(size_t)r * HIDq + j*16];
    }
  }
}

// ---- FALLBACK scan (round-7, verbatim): community-2 tagged LLC exchange ----
__global__ __launch_bounds__(512, 2) void k_scan(const f16* __restrict__ Vh,
                                                 const f16* __restrict__ d2,
                                                 u32* __restrict__ htag,
                                                 f16* __restrict__ hs_out) {
  __shared__ f16 hL[2][16][520];
  const int bid = blockIdx.x, hf = bid & 1, g = bid >> 1;
  const int tid = threadIdx.x, w = tid >> 6, lane = tid & 63;
  const int l15 = lane & 15, q = lane >> 4;
  const int colbase = 256*hf + 32*w;
  f16x8 Bf[2][16];
#pragma unroll
  for (int j = 0; j < 2; ++j)
#pragma unroll
    for (int kk = 0; kk < 16; ++kk)
      Bf[j][kk] = *(const f16x8*)&Vh[(size_t)(colbase + 16*j + l15) * HIDq + kk*32 + q*8];
  for (int i = tid; i < 1024; i += 512) {
    int r = i >> 6, c = (i & 63) * 8;
    f16x8 z = {};
    *(f16x8*)&hL[0][r][c] = z;
  }
  float dv[2][4];
#pragma unroll
  for (int j = 0; j < 2; ++j)
#pragma unroll
    for (int r = 0; r < 4; ++r)
      dv[j][r] = (float)d2[((size_t)0*64 + 16*g + q*4 + r) * HIDq + colbase + 16*j + l15];
  __syncthreads();
  const int irow = tid >> 5, ic8 = (tid & 31) * 8;
  const int pcol = 256*(hf ^ 1) + ic8;
  for (int t = 0; t < Tt; ++t) {
    const int rb = t & 1, wb = rb ^ 1, slot = t & 1;
    if (hs_out && t > 0) {
#pragma unroll
      for (int c = tid; c < 1024; c += 512) {
        int r = c >> 6, cc = (c & 63) * 8;
        *(f16x8*)&hs_out[((size_t)(16*g + r) * Tt + (t-1)) * HIDq + cc] =
            *(const f16x8*)&hL[rb][r][cc];
      }
    }
    f32x4 a00 = {}, a01 = {}, a10 = {}, a11 = {};
#pragma unroll
    for (int kk = 0; kk < 16; ++kk) {
      f16x8 a = *(const f16x8*)&hL[rb][l15][kk*32 + q*8];
      if (kk & 1) {
        a01 = __builtin_amdgcn_mfma_f32_16x16x32_f16(a, Bf[0][kk], a01, 0, 0, 0);
        a11 = __builtin_amdgcn_mfma_f32_16x16x32_f16(a, Bf[1][kk], a11, 0, 0, 0);
      } else {
        a00 = __builtin_amdgcn_mfma_f32_16x16x32_f16(a, Bf[0][kk], a00, 0, 0, 0);
        a10 = __builtin_amdgcn_mfma_f32_16x16x32_f16(a, Bf[1][kk], a10, 0, 0, 0);
      }
    }
    const u32 tagw = (u32)(t + 1) << 16;
    u16 hbits[2][4];
#pragma unroll
    for (int j = 0; j < 2; ++j) {
      f32x4 s = j ? (a10 + a11) : (a00 + a01);
#pragma unroll
      for (int r = 0; r < 4; ++r) {
        float z = s[r] + dv[j][r];
        union { f16 h; u16 u; } cv; cv.h = (f16)fast_tanh(z);
        hbits[j][r] = cv.u;
        as32(&htag[(size_t)(slot*64 + 16*g + q*4 + r) * HIDq + colbase + 16*j + l15],
             tagw | (u32)cv.u);
      }
    }
#pragma unroll
    for (int j = 0; j < 2; ++j)
#pragma unroll
      for (int r = 0; r < 4; ++r) {
        union { u16 u; f16 h; } cv; cv.u = hbits[j][r];
        hL[wb][q*4 + r][colbase + 16*j + l15] = cv.h;
      }
    if (t < Tt - 1) {
#pragma unroll
      for (int j = 0; j < 2; ++j)
#pragma unroll
        for (int r = 0; r < 4; ++r)
          dv[j][r] = (float)d2[((size_t)(t+1)*64 + 16*g + q*4 + r) * HIDq + colbase + 16*j + l15];
    }
    {
      const u64* pp = (const u64*)&htag[(size_t)(slot*64 + 16*g + irow) * HIDq] + pcol/2;
      u64 v[4];
#pragma unroll
      for (int jj = 0; jj < 4; ++jj) v[jj] = al64(pp + jj);
      for (;;) {
        u32 bad = 0;
#pragma unroll
        for (int jj = 0; jj < 4; ++jj)
          bad |= ((u32)v[jj] ^ tagw) | ((u32)(v[jj] >> 32) ^ tagw);
        if ((bad & 0xFFFF0000u) == 0) break;
#pragma unroll
        for (int jj = 0; jj < 4; ++jj) v[jj] = al64(pp + jj);
      }
      union { u32 wd[4]; f16x8 vv; } fr;
#pragma unroll
      for (int jj = 0; jj < 4; ++jj)
        fr.wd[jj] = __builtin_amdgcn_perm((u32)(v[jj] >> 32), (u32)v[jj], 0x05040100u);
      *(f16x8*)&hL[wb][irow][pcol] = fr.vv;
    }
    __syncthreads();
  }
  if (hs_out) {
#pragma unroll
    for (int c = tid; c < 1024; c += 512) {
      int r = c >> 6, cc = (c & 63) * 8;
      *(f16x8*)&hs_out[((size_t)(16*g + r) * Tt + (Tt-1)) * HIDq + cc] =
          *(const f16x8*)&hL[0][r][cc];
    }
  }
}

// ---- final (big path): out = h_last[64,512] @ fc_w^T + fc_b; h plain f16 ----
__global__ __launch_bounds__(64) void k_final16(const f16* __restrict__ h, const f16* __restrict__ fw,
                                                const f16* __restrict__ fb, void* __restrict__ outv,
                                                const int* __restrict__ dmode) {
  __shared__ f16 hA[16][520];
  __shared__ f16 Bw[16][520];
  const int mb = blockIdx.x & 3, nb = blockIdx.x >> 2;
  const int lane = threadIdx.x, l15 = lane & 15, q = lane >> 4;
  for (int i = lane; i < 16 * 64; i += 64) {
    int r = i >> 6, c = (i & 63) * 8;
    *(f16x8*)&hA[r][c] = *(const f16x8*)&h[(size_t)(mb*16 + r) * 512 + c];
    *(f16x8*)&Bw[r][c] = *(const f16x8*)&fw[(size_t)(nb*16 + r) * 512 + c];
  }
  __syncthreads();
  f32x4 acc = {};
#pragma unroll
  for (int kk = 0; kk < 16; ++kk) {
    f16x8 a = *(const f16x8*)&hA[l15][kk*32 + q*8];
    f16x8 b = *(const f16x8*)&Bw[l15][kk*32 + q*8];
    acc = __builtin_amdgcn_mfma_f32_16x16x32_f16(a, b, acc, 0, 0, 0);
  }
  float bv = (float)fb[nb*16 + l15];
  int md = *dmode;
#pragma unroll
  for (int r = 0; r < 4; ++r) {
    int idx = (mb*16 + q*4 + r) * 128 + nb*16 + l15;
    float val = acc[r] + bv;
    if (md) ((float*)outv)[idx] = val;
    else    ((u16*)outv)[idx]   = f2bf(val);
  }
}

// ---- final (fallback path): h from tagged buffer ----
__global__ __launch_bounds__(64) void k_final(const u32* __restrict__ h, const f16* __restrict__ fw,
                                              const f16* __restrict__ fb, void* __restrict__ outv,
                                              const int* __restrict__ dmode) {
  __shared__ f16 hA[16][520];
  __shared__ f16 Bw[16][520];
  const int mb = blockIdx.x & 3, nb = blockIdx.x >> 2;
  const int lane = threadIdx.x, l15 = lane & 15, q = lane >> 4;
  for (int i = lane; i < 16 * 128; i += 64) {
    int r = i >> 7, c = (i & 127) * 4;
    const u64* p = (const u64*)&h[(size_t)(mb*16 + r) * 512 + c];
    u64 v0 = al64(p), v1 = al64(p + 1);
    *(u32*)&hA[r][c]     = __builtin_amdgcn_perm((u32)(v0 >> 32), (u32)v0, 0x05040100u);
    *(u32*)&hA[r][c + 2] = __builtin_amdgcn_perm((u32)(v1 >> 32), (u32)v1, 0x05040100u);
  }
  for (int i = lane; i < 16 * 64; i += 64) {
    int r = i >> 6, c = (i & 63) * 8;
    *(f16x8*)&Bw[r][c] = *(const f16x8*)&fw[(size_t)(nb*16 + r) * 512 + c];
  }
  __syncthreads();
  f32x4 acc = {};
#pragma unroll
  for (int kk = 0; kk < 16; ++kk) {
    f16x8 a = *(const f16x8*)&hA[l15][kk*32 + q*8];
    f16x8 b = *(const f16x8*)&Bw[l15][kk*32 + q*8];
    acc = __builtin_amdgcn_mfma_f32_16x16x32_f16(a, b, acc, 0, 0, 0);
  }
  float bv = (float)fb[nb*16 + l15];
  int md = *dmode;
#pragma unroll
  for (int r = 0; r < 4; ++r) {
    int idx = (mb*16 + q*4 + r) * 128 + nb*16 + l15;
    float val = acc[r] + bv;
    if (md) ((float*)outv)[idx] = val;
    else    ((u16*)outv)[idx]   = f2bf(val);
  }
}

extern "C" void kernel_launch(void* const* d_in, const int* in_sizes, int n_in,
                              void* d_out, int out_size, void* d_ws, size_t ws_size,
                              hipStream_t stream) {
  if (ws_size < 88080384ull) {
    k_zero<<<32, 256, 0, stream>>>((u16*)d_out);
    return;
  }
  char* ws = (char*)d_ws;
  u32* hb1   = (u32*)(ws + 0);         // tagged h (fallback), 256 KB
  u32* hb2   = (u32*)(ws + 262144);    // tagged h (fallback), 256 KB
  int* dmode = (int*)(ws + 524288);
  f16* hlast2 = (f16*)(ws + 589824);   // 64 KB (big path)
  f16* Wx0f = (f16*)(ws + 1048576);
  f16* Uc0f = (f16*)(ws + 1179648);
  f16* Vh0f = (f16*)(ws + 1441792);
  f16* Wx1f = (f16*)(ws + 1966080);
  f16* Uc1f = (f16*)(ws + 2228224);
  f16* Vh1f = (f16*)(ws + 2490368);
  f16* fcwf = (f16*)(ws + 3014656);
  f16* bx0f = (f16*)(ws + 3145728);
  f16* bx1f = (f16*)(ws + 3146240);
  f16* fcbf = (f16*)(ws + 3146752);
  f16* x16  = (f16*)(ws + 4194304);    // 16 MB
  f16* A    = (f16*)(ws + 20971520);   // 32 MB: db1 | xp2+cb2
  f16* Xb   = (f16*)(ws + 54525952);   // 32 MB: xp1+cb1 | hs1 | db2
  f16* xp1 = Xb;
  f16* cb1 = Xb + 8388608;
  f16* db1 = A;                        // time-major [t][b][hid]
  f16* hs1 = Xb;
  f16* xp2 = A;
  f16* cb2 = A + 8388608;
  f16* db2 = Xb;                       // time-major

  // runtime capability check for the 148 KB-LDS scan (host query; graph-capture safe)
  int dev = 0, maxlds = 0;
  (void)hipGetDevice(&dev);
  (void)hipDeviceGetAttribute(&maxlds, hipDeviceAttributeMaxSharedMemoryPerBlock, dev);
  bool big = (maxlds >= SCAN4_LDS);
  if (big)
    (void)hipFuncSetAttribute((const void*)k_scan4,
                              hipFuncAttributeMaxDynamicSharedMemorySize, SCAN4_LDS);

  k_probe<<<1, 256, 0, stream>>>((const u16*)d_in[1], dmode);
  auto cvt = [&](const void* s, f16* d, int n) {
    int n8 = n / 8;
    k_cvt<<<dim3((n8 + 255) / 256), dim3(256), 0, stream>>>(s, d, n8, dmode);
  };
  cvt(d_in[0],  x16,  8388608);
  cvt(d_in[1],  Wx0f, 65536);
  cvt(d_in[2],  bx0f, 256);
  cvt(d_in[3],  Uc0f, 131072);
  cvt(d_in[4],  Vh0f, 262144);
  cvt(d_in[5],  Wx1f, 131072);
  cvt(d_in[6],  bx1f, 256);
  cvt(d_in[7],  Uc1f, 131072);
  cvt(d_in[8],  Vh1f, 262144);
  cvt(d_in[9],  fcwf, 65536);
  cvt(d_in[10], fcbf, 128);

  // layer 1
  k_gemm<true , false><<<dim3(2, 256), 256, 0, stream>>>(x16, Wx0f, bx0f, xp1, 32768, 256, 256);
  k_ema<<<512, 128, 0, stream>>>(xp1, cb1);
  k_gemm<false, true ><<<dim3(4, 256), 256, 0, stream>>>(cb1, Uc0f, nullptr, db1, 32768, 512, 256);
  if (big) k_scan4<<<4, 512, SCAN4_LDS, stream>>>(Vh0f, db1, hs1, nullptr);
  else     k_scan<<<8, 512, 0, stream>>>(Vh0f, db1, hb1, hs1);
  // layer 2
  k_gemm<true , false><<<dim3(2, 256), 256, 0, stream>>>(hs1, Wx1f, bx1f, xp2, 32768, 256, 512);
  k_ema<<<512, 128, 0, stream>>>(xp2, cb2);
  k_gemm<false, true ><<<dim3(4, 256), 256, 0, stream>>>(cb2, Uc1f, nullptr, db2, 32768, 512, 256);
  if (big) {
    k_scan4<<<4, 512, SCAN4_LDS, stream>>>(Vh1f, db2, nullptr, hlast2);
    k_final16<<<32, 64, 0, stream>>>(hlast2, fcwf, fcbf, d_out, dmode);
  } else {
    k_scan<<<8, 512, 0, stream>>>(Vh1f, db2, hb2, nullptr);
    k_final<<<32, 64, 0, stream>>>(hb2 + 64 * 512, fcwf, fcbf, d_out, dmode);
  }
}